// Round 5
// baseline (37.646 us; speedup 1.0000x reference)
//
#include <hip/hip_runtime.h>
#include <math.h>
#include <float.h>

#define BATCH 1024
#define DIM 128
#define EPSV 1e-12f
#define MARGIN 0.5f
#define INTRA_MARGIN 0.1f
#define LAMDA 0.5f

typedef __attribute__((ext_vector_type(8))) short s16x8;   // 8 bf16 (4 VGPRs)
typedef __attribute__((ext_vector_type(4))) float f32x4;   // MFMA C/D

__device__ __forceinline__ ushort f2bf(float f) {          // RNE fp32 -> bf16
    unsigned u = __float_as_uint(f);
    return (ushort)((u + 0x7fffu + ((u >> 16) & 1u)) >> 16);
}

// convert 8 fp32 -> bf16x8 fragment, accumulating sum-of-squares (exact fp32)
__device__ __forceinline__ s16x8 cvt8(float4 a, float4 b, float& ss) {
    s16x8 r;
    r[0] = (short)f2bf(a.x); ss = fmaf(a.x, a.x, ss);
    r[1] = (short)f2bf(a.y); ss = fmaf(a.y, a.y, ss);
    r[2] = (short)f2bf(a.z); ss = fmaf(a.z, a.z, ss);
    r[3] = (short)f2bf(a.w); ss = fmaf(a.w, a.w, ss);
    r[4] = (short)f2bf(b.x); ss = fmaf(b.x, b.x, ss);
    r[5] = (short)f2bf(b.y); ss = fmaf(b.y, b.y, ss);
    r[6] = (short)f2bf(b.z); ss = fmaf(b.z, b.z, ss);
    r[7] = (short)f2bf(b.w); ss = fmaf(b.w, b.w, ss);
    return r;
}

// Single fused kernel: 128 blocks x 512 threads (8 waves).
// Block = 16 rows (one half) x ALL 1024 cols (other half); wave w owns cols
// [w*128, w*128+128) as 8 subtiles of 16. fp32->bf16 conversion + norms done
// in-register; exact-fp32 intra gather; last-block deterministic final sum.
__global__ __launch_bounds__(512) void bidir_fused_kernel(
    const float* __restrict__ feat,
    const int* __restrict__ label1, const int* __restrict__ label2,
    float* __restrict__ partial, unsigned int* __restrict__ counter,
    float* __restrict__ out)
{
    const int bid   = blockIdx.x;            // 0..127
    const int half  = bid >> 6;              // 64 blocks per half
    const int arow0 = (bid & 63) * 16;       // row base within half

    const int t = threadIdx.x;
    const int w = t >> 6, lane = t & 63;
    const int l15 = lane & 15, kg = lane >> 4;

    const float* fA = feat + (size_t)half * BATCH * DIM;
    const float* fB = feat + (size_t)(half ^ 1) * BATCH * DIM;  // b-side = f_intra
    const int* labA = half ? label2 : label1;
    const int* labB = half ? label1 : label2;

    int jcol[8]; size_t boff[8]; int lb[8];
    #pragma unroll
    for (int s = 0; s < 8; ++s) {
        jcol[s] = w * 128 + s * 16 + l15;
        boff[s] = (size_t)jcol[s] * DIM;
        lb[s]   = labB[jcol[s]];
    }
    const size_t aoff = (size_t)(arow0 + l15) * DIM;

    float naL = 0.0f;          // ||A row l15||^2 partial (this lane's 32 elems)
    float nbL[8];              // ||B col jcol[s]||^2 partials
    #pragma unroll
    for (int s = 0; s < 8; ++s) nbL[s] = 0.0f;

    f32x4 acc[8];
    #pragma unroll
    for (int s = 0; s < 8; ++s) acc[s] = (f32x4){0.f, 0.f, 0.f, 0.f};

    #pragma unroll
    for (int kt = 0; kt < 4; ++kt) {
        const int koff = kt * 32 + kg * 8;
        const float4* pa = reinterpret_cast<const float4*>(fA + aoff + koff);
        const s16x8 ah = cvt8(pa[0], pa[1], naL);
        #pragma unroll
        for (int s = 0; s < 8; ++s) {
            const float4* pb = reinterpret_cast<const float4*>(fB + boff[s] + koff);
            const s16x8 bh = cvt8(pb[0], pb[1], nbL[s]);
            acc[s] = __builtin_amdgcn_mfma_f32_16x16x32_bf16(ah, bh, acc[s], 0, 0, 0);
        }
    }

    // complete norms across the 4 k-groups (lane bits 4 and 5 = kg)
    naL += __shfl_xor(naL, 16); naL += __shfl_xor(naL, 32);
    #pragma unroll
    for (int s = 0; s < 8; ++s) {
        nbL[s] += __shfl_xor(nbL[s], 16);
        nbL[s] += __shfl_xor(nbL[s], 32);
    }

    // ---- selection in d^2 domain; C/D layout: col=l15, row=kg*4+reg ----
    // na for C row (kg*4+r) lives in lanes whose l15 == that row -> shfl from lane kg*4+r
    float na[4]; int la[4];
    #pragma unroll
    for (int r = 0; r < 4; ++r) {
        na[r] = __shfl(naL, kg * 4 + r);
        la[r] = labA[arow0 + kg * 4 + r];
    }

    float bpv[4], bnv[4]; int bpj[4], bnj[4];
    #pragma unroll
    for (int r = 0; r < 4; ++r) { bpv[r] = -1.0f; bpj[r] = 0x7fffffff; bnv[r] = FLT_MAX; bnj[r] = 0x7fffffff; }

    #pragma unroll
    for (int s = 0; s < 8; ++s) {
        #pragma unroll
        for (int r = 0; r < 4; ++r) {
            const float d2 = fmaxf(na[r] + nbL[s] - 2.0f * acc[s][r], 0.0f);
            const bool same = (la[r] == lb[s]);
            const float pv = same ? d2 : 0.0f;
            const float nv = same ? FLT_MAX : d2;
            // jcol ascending in s -> strict compares keep first occurrence
            if (pv > bpv[r]) { bpv[r] = pv; bpj[r] = jcol[s]; }
            if (nv < bnv[r]) { bnv[r] = nv; bnj[r] = jcol[s]; }
        }
    }

    // reduce across the 16 lanes of each row group (masks < 16 keep kg fixed)
    #pragma unroll
    for (int r = 0; r < 4; ++r) {
        #pragma unroll
        for (int m = 8; m > 0; m >>= 1) {
            const float opv = __shfl_xor(bpv[r], m); const int opj = __shfl_xor(bpj[r], m);
            if (opv > bpv[r] || (opv == bpv[r] && opj < bpj[r])) { bpv[r] = opv; bpj[r] = opj; }
            const float onv = __shfl_xor(bnv[r], m); const int onj = __shfl_xor(bnj[r], m);
            if (onv < bnv[r] || (onv == bnv[r] && onj < bnj[r])) { bnv[r] = onv; bnj[r] = onj; }
        }
    }

    // ---- cross-wave combine: 16 rows x 8 col-chunks ----
    __shared__ float L_pv[16][8]; __shared__ int L_pj[16][8];
    __shared__ float L_nv[16][8]; __shared__ int L_nj[16][8];
    if (l15 == 0) {
        #pragma unroll
        for (int r = 0; r < 4; ++r) {
            const int rib = kg * 4 + r;
            L_pv[rib][w] = bpv[r]; L_pj[rib][w] = bpj[r];
            L_nv[rib][w] = bnv[r]; L_nj[rib][w] = bnj[r];
        }
    }
    __syncthreads();

    __shared__ int s_pp[16], s_pn[16];
    __shared__ float s_fp[16], s_cn[16];
    if (t < 16) {
        float pv = -1.0f; int pj = 0x7fffffff; float nv = FLT_MAX; int nj = 0x7fffffff;
        #pragma unroll
        for (int c = 0; c < 8; ++c) {   // ascending col ranges -> tie keeps first
            const float v1 = L_pv[t][c]; const int j1 = L_pj[t][c];
            if (v1 > pv || (v1 == pv && j1 < pj)) { pv = v1; pj = j1; }
            const float v2 = L_nv[t][c]; const int j2 = L_nj[t][c];
            if (v2 < nv || (v2 == nv && j2 < nj)) { nv = v2; nj = j2; }
        }
        s_pp[t] = pj > (BATCH - 1) ? (BATCH - 1) : pj;
        s_pn[t] = nj > (BATCH - 1) ? (BATCH - 1) : nj;
        s_fp[t] = (pv > 0.0f) ? sqrtf(pv + EPSV) : 0.0f;   // no-positive row -> 0
        s_cn[t] = sqrtf(nv + EPSV);
    }
    __syncthreads();

    // ---- intra distances (exact fp32): 16 rows x 16 lanes ----
    __shared__ float ls[16];
    if (t < 256) {
        const int g = t >> 4, sl = t & 15;
        const float4* x = reinterpret_cast<const float4*>(fB + (size_t)s_pp[g] * DIM + sl * 8);
        const float4* y = reinterpret_cast<const float4*>(fB + (size_t)s_pn[g] * DIM + sl * 8);
        const float4 x0 = x[0], x1 = x[1], y0 = y[0], y1 = y[1];
        float d, d2;
        d = x0.x - y0.x; d2  = d * d;  d = x0.y - y0.y; d2 += d * d;
        d = x0.z - y0.z; d2 += d * d;  d = x0.w - y0.w; d2 += d * d;
        d = x1.x - y1.x; d2 += d * d;  d = x1.y - y1.y; d2 += d * d;
        d = x1.z - y1.z; d2 += d * d;  d = x1.w - y1.w; d2 += d * d;
        d2 += __shfl_xor(d2, 1); d2 += __shfl_xor(d2, 2);
        d2 += __shfl_xor(d2, 4); d2 += __shfl_xor(d2, 8);
        if (sl == 0) {
            const float gd = sqrtf(d2 + EPSV);
            const float loss = fmaxf(s_fp[g] - s_cn[g] + MARGIN, 0.0f)
                             + LAMDA * fmaxf(INTRA_MARGIN - gd, 0.0f);
            ls[g] = loss * (1.0f / (float)BATCH);
        }
    }
    __syncthreads();

    // ---- per-block partial + last-block deterministic final sum ----
    if (t == 0) {
        float s = 0.0f;
        #pragma unroll
        for (int i = 0; i < 16; ++i) s += ls[i];
        partial[bid] = s;
        __threadfence();
        const unsigned int old = atomicAdd(counter, 1u);
        if (old == 127u) {
            __threadfence();
            float tot = 0.0f;
            for (int i = 0; i < 128; ++i) tot += partial[i];   // fixed order -> deterministic
            out[0] = tot;
        }
    }
}

extern "C" void kernel_launch(void* const* d_in, const int* in_sizes, int n_in,
                              void* d_out, int out_size, void* d_ws, size_t ws_size,
                              hipStream_t stream) {
    const float* feat   = (const float*)d_in[0];
    const int*   label1 = (const int*)d_in[1];
    const int*   label2 = (const int*)d_in[2];
    float* out = (float*)d_out;

    char* ws = (char*)d_ws;
    float*        partial = (float*)(ws);           // 512 B
    unsigned int* counter = (unsigned int*)(ws + 1024);

    hipMemsetAsync(counter, 0, sizeof(unsigned int), stream);  // graph-capturable node
    bidir_fused_kernel<<<dim3(128), dim3(512), 0, stream>>>(
        feat, label1, label2, partial, counter, out);
}